// Round 4
// baseline (405.238 us; speedup 1.0000x reference)
//
#include <hip/hip_runtime.h>
#include <cstdint>

#pragma clang fp contract(off)

constexpr int cB = 16;
constexpr int cN = 22743;
constexpr int cROW = 85;
constexpr int cK = 1000;
constexpr float CONF_T = 0.5f;
constexpr float NMS_T = 0.4f;

// ---------------- kernel 1: per-row score -> orderable uint key ----------------
// Stage 128 rows into LDS coalesced; TWO threads per row, 4-accumulator ILP
// (chain depth 80 -> ~12), pair-combine via one shfl_xor. ~HBM floor (~20 us).
__global__ __launch_bounds__(256) void k_score(const float* __restrict__ in,
                                               unsigned* __restrict__ ukey) {
  __shared__ float sdata[10880];              // 128 rows x 85 floats = 43.52 KB
  constexpr int F4_PER_BLK = 2720;            // 10880 / 4
  constexpr int TOTAL_F4 = (cB * cN * cROW) / 4;
  int tid = threadIdx.x;
  const float4* gin4 = (const float4*)in;
  float4* s4 = (float4*)sdata;
  int base_f4 = blockIdx.x * F4_PER_BLK;
#pragma unroll
  for (int q = 0; q < 11; ++q) {
    int k = tid + 256 * q;
    if (k < F4_PER_BLK) {
      int g = base_f4 + k;
      if (g < TOTAL_F4) s4[k] = gin4[g];
    }
  }
  __syncthreads();
  int r = tid >> 1, h = tid & 1;              // pair (2r,2r+1) -> row r
  int grow = blockIdx.x * 128 + r;
  if (grow < cB * cN) {
    const float* rowp = sdata + cROW * r;
    int j0 = 5 + h * 40;                      // h=0: classes 0..39, h=1: 40..79
    float m0 = rowp[j0 + 0], m1 = rowp[j0 + 1];
    float m2 = rowp[j0 + 2], m3 = rowp[j0 + 3];
#pragma unroll
    for (int k = 4; k < 40; k += 4) {
      m0 = fmaxf(m0, rowp[j0 + k + 0]);
      m1 = fmaxf(m1, rowp[j0 + k + 1]);
      m2 = fmaxf(m2, rowp[j0 + k + 2]);
      m3 = fmaxf(m3, rowp[j0 + k + 3]);
    }
    float m = fmaxf(fmaxf(m0, m1), fmaxf(m2, m3));
    m = fmaxf(m, __shfl_xor(m, 1));           // partner lane = same row, other half
    if (h == 0) {
      float obj = rowp[4];
      unsigned u = 0u;
      if (obj >= CONF_T) {
        float s = obj * m;
        if (s > 0.0f) u = __float_as_uint(s);
      }
      ukey[grow] = u;
    }
  }
}

// ---------------- bitonic sort (u32 asc; only for the rare exact-tie path) ----
__device__ __forceinline__ void sort1024_u32_asc(unsigned* a, int tid) {
  for (int k = 2; k <= 1024; k <<= 1) {
    for (int j = k >> 1; j >= 1; j >>= 1) {
      __syncthreads();
      if (tid < 512) {
        int i = ((tid & ~(j - 1)) << 1) | (tid & (j - 1));
        int p = i | j;
        unsigned x = a[i], y = a[p];
        bool up = ((i & k) == 0);
        bool sw = up ? (x > y) : (x < y);
        if (sw) { a[i] = y; a[p] = x; }
      }
    }
  }
  __syncthreads();
}

// ---------------- kernel 2: exact top-1000 + GATHER fused (R11) ----------------
// Radix-select (R1 histogram form), 2-D rank split (R10, now G=8 k-groups),
// then the former k_gather runs in this block's tail: topidx scattered to LDS,
// 16 waves gather 1000 rows with 2-slot ILP. Removes one launch+gap, the
// topidx round-trip for gather, and the validv buffer entirely (k3 tests
// topidx>=0). Also zeroes cnt[img] for k3's last-block pattern (workspace is
// poisoned by the harness each iteration).
__global__ __launch_bounds__(1024) void k_topk(const unsigned* __restrict__ ukey,
                                               const float* __restrict__ in,
                                               int* __restrict__ topidx,
                                               float4* __restrict__ boxes,
                                               float* __restrict__ area,
                                               float* __restrict__ objv,
                                               float* __restrict__ confv,
                                               int* __restrict__ clsv,
                                               unsigned* __restrict__ cnt) {
  __shared__ unsigned hist[2048];             // 8 KB
  __shared__ unsigned wtot[16];
  __shared__ unsigned long long cand[1024];   // 8 KB
  __shared__ unsigned eqbuf[1024];            // 4 KB (tie path only)
  __shared__ unsigned praw[8][1024];          // 32 KB (rank partials, G=8)
  __shared__ int sh_topidx[1024];             // 4 KB (gather phase)
  __shared__ unsigned sh_T, sh_newrank, sh_E, sh_cnt;
  int img = blockIdx.x;
  int tid = threadIdx.x;
  int lane = tid & 63;
  int wv = tid >> 6;
  const unsigned* uk = ukey + (size_t)img * cN;

  if (tid == 0) cnt[img] = 0u;                // k3 runs later in stream order

  constexpr int NIT = (cN + 1023) / 1024;     // 23
  unsigned uv[NIT];
#pragma unroll
  for (int q = 0; q < NIT; ++q) {
    int i = q * 1024 + tid;
    uv[q] = (i < cN) ? uk[i] : 0u;            // 23 independent loads in flight
  }

  unsigned prefix = 0;
  int bits = 0;
  unsigned rank = cK;
  unsigned gtc = 0;   // count of keys strictly greater than current prefix block
  unsigned E = 0;     // count of keys equal to current prefix block

  for (int r = 0; r < 3; ++r) {
    int nb = (r < 2) ? 11 : 10;
    int shift = 32 - bits - nb;
    hist[tid] = 0u; hist[tid + 1024] = 0u;
    __syncthreads();
#pragma unroll
    for (int q = 0; q < NIT; ++q) {
      unsigned u = uv[q];
      bool inr = (q * 1024 + tid) < cN;
      bool match = inr && (bits == 0 || (u >> (32 - bits)) == prefix);
      bool isz = match && (u == 0u);
      bool nz = match && (u != 0u);
      // zeros all hit bin 0 -> aggregate to one atomic per wave
      unsigned long long mz = __ballot(isz);
      if (isz && lane == (__ffsll((long long)mz) - 1))
        atomicAdd(&hist[0], (unsigned)__popcll(mz));
      if (nz) atomicAdd(&hist[(u >> shift) & ((1u << nb) - 1u)], 1u);
    }
    __syncthreads();
    // hierarchical suffix scan over 2048 bins: pair-sum -> in-wave shfl suffix
    // -> 16 wave totals -> broadcast add. 3 barriers total.
    unsigned h0 = hist[2 * tid];
    unsigned h1 = hist[2 * tid + 1];
    unsigned s2 = h0 + h1;
#pragma unroll
    for (int s = 1; s < 64; s <<= 1) {
      unsigned t = __shfl_down(s2, s);
      s2 += (lane + s < 64) ? t : 0u;
    }
    if (lane == 0) wtot[wv] = s2;             // wave total (inclusive suffix at lane 0)
    __syncthreads();
    unsigned above = 0;
    for (int w2 = wv + 1; w2 < 16; ++w2) above += wtot[w2];
    unsigned S_even = above + s2;             // suffix(bin 2*tid)
    unsigned S_odd = S_even - h0;             // suffix(bin 2*tid+1)
    unsigned S_next = S_odd - h1;             // suffix(bin 2*tid+2); 0 at tid=1023
    if (S_even >= rank && S_odd < rank) { sh_T = 2u * tid; sh_newrank = rank - S_odd; sh_E = h0; }
    if (S_odd >= rank && S_next < rank) { sh_T = 2u * tid + 1u; sh_newrank = rank - S_next; sh_E = h1; }
    __syncthreads();
    unsigned T = sh_T;
    unsigned nr = sh_newrank;
    E = sh_E;
    gtc += rank - nr;
    rank = nr;
    prefix = (prefix << nb) | T;
    bits += nb;
    __syncthreads();           // hist reused next round
    if (gtc + E <= 1024u) break;
  }

  bool tiepath = (gtc + E > 1024u);   // only possible at bits==32 (exact ties)
  unsigned pivotLo = (bits >= 32) ? prefix : (prefix << (32 - bits));
  cand[tid] = (unsigned long long)tid;   // distinct filler keys, high32 = 0
  eqbuf[tid] = 0xFFFFFFFFu;
  if (tid == 0) sh_cnt = 0u;
  __syncthreads();

  if (!tiepath) {
#pragma unroll
    for (int q = 0; q < NIT; ++q) {
      int i = q * 1024 + tid;
      unsigned u = uv[q];
      bool m = (i < cN) && (u >= pivotLo);
      unsigned long long mb = __ballot(m);
      if (m) {
        int ldr = __ffsll((long long)mb) - 1;
        unsigned base = 0;
        if (lane == ldr) base = atomicAdd(&sh_cnt, (unsigned)__popcll(mb));
        base = __shfl(base, ldr);
        unsigned pos = base + (unsigned)__popcll(mb & ((1ull << lane) - 1ull));
        if (pos < 1024u)
          cand[pos] = ((unsigned long long)u << 32) |
                      (unsigned long long)(0xFFFFFFFFu - (unsigned)i);
      }
    }
    __syncthreads();
  } else {
    // exact-tie fallback: u > P into cand, u == P smallest indices appended
    unsigned P = prefix;
#pragma unroll
    for (int q = 0; q < NIT; ++q) {
      int i = q * 1024 + tid;
      unsigned u = uv[q];
      bool gt = (i < cN) && (u > P);
      unsigned long long mb = __ballot(gt);
      if (gt) {
        int ldr = __ffsll((long long)mb) - 1;
        unsigned base = 0;
        if (lane == ldr) base = atomicAdd(&sh_cnt, (unsigned)__popcll(mb));
        base = __shfl(base, ldr);
        unsigned pos = base + (unsigned)__popcll(mb & ((1ull << lane) - 1ull));
        if (pos < 1024u)
          cand[pos] = ((unsigned long long)u << 32) |
                      (unsigned long long)(0xFFFFFFFFu - (unsigned)i);
      }
    }
    __syncthreads();
    if (tid == 0) sh_E = 0u;
    __syncthreads();
#pragma unroll
    for (int q = 0; q < NIT; ++q) {
      int i = q * 1024 + tid;
      unsigned u = uv[q];
      bool eq = (i < cN) && (u == P);
      unsigned long long mb = __ballot(eq);
      if (eq) {
        int ldr = __ffsll((long long)mb) - 1;
        unsigned base = 0;
        if (lane == ldr) base = atomicAdd(&sh_E, (unsigned)__popcll(mb));
        base = __shfl(base, ldr);
        unsigned pos = base + (unsigned)__popcll(mb & ((1ull << lane) - 1ull));
        if (pos < 1024u) eqbuf[pos] = (unsigned)i;
      }
    }
    __syncthreads();
    sort1024_u32_asc(eqbuf, tid);
    int need = (int)cK - (int)gtc;
    for (int t = tid; t < need; t += 1024) {
      unsigned idx = eqbuf[t];
      if (idx != 0xFFFFFFFFu)
        cand[gtc + (unsigned)t] = ((unsigned long long)P << 32) |
                                  (unsigned long long)(0xFFFFFFFFu - idx);
    }
    __syncthreads();
  }

  // ---- rank-by-count, 2-D split, G=8 (R11) ----
  // 16 waves = 2 j-groups (jg) x 8 k-groups (kg). Lane owns 8 j's in regs.
  {
    int kg = wv & 7, jg = wv >> 3;
    unsigned long long myv[8];
#pragma unroll
    for (int m = 0; m < 8; ++m) myv[m] = cand[jg * 512 + m * 64 + lane];
    unsigned c[8];
#pragma unroll
    for (int m = 0; m < 8; ++m) c[m] = 0u;
    int k0 = kg * 128;
#pragma unroll 4
    for (int k = 0; k < 128; ++k) {
      unsigned long long ck = cand[k0 + k];   // wave-uniform broadcast read
#pragma unroll
      for (int m = 0; m < 8; ++m) c[m] += (ck > myv[m]) ? 1u : 0u;
    }
#pragma unroll
    for (int m = 0; m < 8; ++m) praw[kg][jg * 512 + m * 64 + lane] = c[m];
  }
  __syncthreads();
  unsigned rk = 0;
#pragma unroll
  for (int g = 0; g < 8; ++g) rk += praw[g][tid];
  unsigned long long my = cand[tid];
  sh_topidx[tid] = -1;
  __syncthreads();
  if (rk < (unsigned)cK) {
    unsigned uhi = (unsigned)(my >> 32);
    int idx = (int)(0xFFFFFFFFu - (unsigned)(my & 0xFFFFFFFFull));
    int oi = (uhi > 0u) ? idx : -1;
    topidx[img * cK + (int)rk] = oi;          // k3's valid mask source
    sh_topidx[(int)rk] = oi;
  }
  __syncthreads();

  // ---- gather phase (former k_gather), 2 slots/wave-iter for ILP ----
  for (int j = 0; j < 32; ++j) {
    int s0 = wv + 32 * j;
    int s1 = s0 + 16;
    int i0 = (s0 < cK) ? sh_topidx[s0] : -1;
    int i1 = (s1 < cK) ? sh_topidx[s1] : -1;
    const float* r0 = in + ((size_t)img * cN + (size_t)(i0 < 0 ? 0 : i0)) * cROW;
    const float* r1 = in + ((size_t)img * cN + (size_t)(i1 < 0 ? 0 : i1)) * cROW;
    float va = r0[5 + lane];
    float vb = r1[5 + lane];
    int ca = lane, cb = lane;
    if (lane < 16) {
      float v2a = r0[69 + lane];
      float v2b = r1[69 + lane];
      if (v2a > va) { va = v2a; ca = 64 + lane; }
      if (v2b > vb) { vb = v2b; cb = 64 + lane; }
    }
#pragma unroll
    for (int m = 1; m < 64; m <<= 1) {
      float ova = __shfl_xor(va, m); int oca = __shfl_xor(ca, m);
      float ovb = __shfl_xor(vb, m); int ocb = __shfl_xor(cb, m);
      if (ova > va || (ova == va && oca < ca)) { va = ova; ca = oca; }
      if (ovb > vb || (ovb == vb && ocb < cb)) { vb = ovb; cb = ocb; }
    }
    if (lane == 0) {
      if (s0 < cK) {
        int wid = img * cK + s0;
        if (i0 < 0) {
          boxes[wid] = make_float4(0.f, 0.f, 0.f, 0.f);
          area[wid] = 0.f; objv[wid] = 0.f; confv[wid] = 0.f; clsv[wid] = -1;
        } else {
          float cx = r0[0], cy = r0[1], w = r0[2], h = r0[3], ob = r0[4];
          float hw = w * 0.5f, hh = h * 0.5f;
          float x1 = cx - hw, y1 = cy - hh, x2 = cx + hw, y2 = cy + hh;
          boxes[wid] = make_float4(x1, y1, x2, y2);
          area[wid] = fmaxf(x2 - x1, 0.f) * fmaxf(y2 - y1, 0.f);
          objv[wid] = ob; confv[wid] = va; clsv[wid] = ca;
        }
      }
      if (s1 < cK) {
        int wid = img * cK + s1;
        if (i1 < 0) {
          boxes[wid] = make_float4(0.f, 0.f, 0.f, 0.f);
          area[wid] = 0.f; objv[wid] = 0.f; confv[wid] = 0.f; clsv[wid] = -1;
        } else {
          float cx = r1[0], cy = r1[1], w = r1[2], h = r1[3], ob = r1[4];
          float hw = w * 0.5f, hh = h * 0.5f;
          float x1 = cx - hw, y1 = cy - hh, x2 = cx + hw, y2 = cy + hh;
          boxes[wid] = make_float4(x1, y1, x2, y2);
          area[wid] = fmaxf(x2 - x1, 0.f) * fmaxf(y2 - y1, 0.f);
          objv[wid] = ob; confv[wid] = vb; clsv[wid] = cb;
        }
      }
    }
  }
}

// ---------------- kernel 3: suppress bitmask + LAST-BLOCK greedy NMS (R11) ----
// St[img][w][i] (i padded to 1024): word w of suppress-row i. The 128th block
// to finish an image (device-scope counter, rocPRIM last-block pattern with
// release/acquire threadfences for cross-XCD St visibility) runs the greedy
// NMS + masked output write. Removes the k_nms launch+gap.
__device__ __forceinline__ unsigned u4c(const uint4& v, int c) {
  return c == 0 ? v.x : c == 1 ? v.y : c == 2 ? v.z : v.w;
}

__device__ __forceinline__ void nms_load(const uint4* __restrict__ colv, int b,
                                         uint4 (&buf)[8]) {
#pragma unroll
  for (int q = 0; q < 8; ++q) buf[q] = colv[8 * b + q];
}

__device__ __forceinline__ void nms_proc(int b, int lane, unsigned& kw,
                                         const uint4 (&W)[8]) {
  unsigned dec = 0u;
  if (lane == b) {
    unsigned kwb = kw;
#pragma unroll
    for (int t = 0; t < 32; ++t) {
      if ((kwb >> t) & 1u) {
        dec |= (1u << t);
        unsigned rw = u4c(W[t >> 2], t & 3);
        unsigned mgt = (t == 31) ? 0u : (0xFFFFFFFFu << (t + 1));
        kwb &= ~(rw & mgt);   // kill only later rows within this word
      }
    }
    kw = kwb;
  }
  dec = __shfl(dec, b);       // broadcast the 32 decisions
  if (dec != 0u && lane > b) {   // skip apply when no kept rows in word b
#pragma unroll
    for (int t = 0; t < 32; ++t) {
      unsigned sel = 0u - ((dec >> t) & 1u);
      kw &= ~(u4c(W[t >> 2], t & 3) & sel);
    }
  }
}

__global__ __launch_bounds__(256) void k_suppress_nms(
    const float4* __restrict__ boxes, const float* __restrict__ area,
    const int* __restrict__ clsv, const float* __restrict__ objv,
    const float* __restrict__ confv, const int* __restrict__ topidx,
    unsigned* __restrict__ St, unsigned* __restrict__ cnt,
    float* __restrict__ out) {
  // +(i>>5) padding: inner-loop bank = (w+bit)%32 -> conflict-free
  __shared__ float sx1[1056], sy1[1056], sx2[1056], sy2[1056], sar[1056];
  __shared__ int scls[1056];
  __shared__ unsigned sh_old;
  __shared__ unsigned keep_sh[32];
  int img = blockIdx.x >> 7;            // / 128
  int rb = (blockIdx.x & 127) * 8;      // 128 blocks x 8 rows = 1024 rows
  int tid = threadIdx.x;
  for (int i = tid; i < 1024; i += 256) {
    int p = i + (i >> 5);
    if (i < cK) {
      float4 b = boxes[img * cK + i];
      sx1[p] = b.x; sy1[p] = b.y; sx2[p] = b.z; sy2[p] = b.w;
      sar[p] = area[img * cK + i];
      scls[p] = clsv[img * cK + i];
    } else {
      sx1[p] = 0.f; sy1[p] = 0.f; sx2[p] = 0.f; sy2[p] = 0.f; sar[p] = 0.f;
      scls[p] = -2;
    }
  }
  __syncthreads();
  {
    int i = rb + (tid >> 5);
    int w = tid & 31;
    int pi = i + (i >> 5);
    float bx1 = sx1[pi], by1 = sy1[pi], bx2 = sx2[pi], by2 = sy2[pi], ba = sar[pi];
    int bc = scls[pi];
    unsigned word = 0u;
#pragma unroll 4
    for (int bit = 0; bit < 32; ++bit) {
      int pj = 33 * w + bit;
      float xx1 = fmaxf(bx1, sx1[pj]);
      float yy1 = fmaxf(by1, sy1[pj]);
      float xx2 = fminf(bx2, sx2[pj]);
      float yy2 = fminf(by2, sy2[pj]);
      float inter = fmaxf(xx2 - xx1, 0.f) * fmaxf(yy2 - yy1, 0.f);
      float uni = ba + sar[pj] - inter;
      float iou = inter / (uni + 1e-16f);
      if (iou > NMS_T && bc == scls[pj]) word |= (1u << bit);
    }
    St[((size_t)(img * 32 + w)) * 1024 + (size_t)i] = word;
  }
  // ---- last-block handoff ----
  __syncthreads();                       // all St stores of this block drained
  if (tid == 0) {
    __threadfence();                     // release: flush St to device scope
    sh_old = atomicAdd(&cnt[img], 1u);
  }
  __syncthreads();
  if (sh_old != 127u) return;            // not last -> done
  if (tid == 0) __threadfence();         // acquire: invalidate stale caches
  __syncthreads();

  // ---- greedy NMS (wave 0, lanes 0..31) ----
  if (tid < 32) {
    const uint4* colv = (const uint4*)(St + ((size_t)(img * 32 + tid)) * 1024);
    unsigned kw = 0u;
    const int4* v4 = (const int4*)(topidx + img * cK);
#pragma unroll
    for (int q = 0; q < 8; ++q) {
      int k0 = (tid << 5) + 4 * q;
      if (k0 < cK) {
        int4 t = v4[tid * 8 + q];
        kw |= (unsigned)(t.x >= 0) << (4 * q + 0);
        kw |= (unsigned)(t.y >= 0) << (4 * q + 1);
        kw |= (unsigned)(t.z >= 0) << (4 * q + 2);
        kw |= (unsigned)(t.w >= 0) << (4 * q + 3);
      }
    }
    uint4 bufA[8], bufB[8];
    nms_load(colv, 0, bufA);
    for (int b = 0; b < 32; b += 2) {
      if (b + 1 < 32) nms_load(colv, b + 1, bufB);
      nms_proc(b, tid, kw, bufA);
      if (b + 2 < 32) nms_load(colv, b + 2, bufA);
      nms_proc(b + 1, tid, kw, bufB);
    }
    keep_sh[tid] = kw;
  }
  __syncthreads();
  // ---- masked output write (all 256 threads) ----
  for (int k = tid; k < cK; k += 256) {
    bool kp = ((keep_sh[k >> 5] >> (k & 31)) & 1u) != 0u;
    size_t o = ((size_t)img * cK + (size_t)k) * 7;
    if (kp) {
      float4 b = boxes[img * cK + k];
      out[o + 0] = b.x; out[o + 1] = b.y; out[o + 2] = b.z; out[o + 3] = b.w;
      out[o + 4] = objv[img * cK + k];
      out[o + 5] = confv[img * cK + k];
      out[o + 6] = (float)clsv[img * cK + k];
    } else {
      out[o + 0] = 0.f; out[o + 1] = 0.f; out[o + 2] = 0.f; out[o + 3] = 0.f;
      out[o + 4] = 0.f; out[o + 5] = 0.f; out[o + 6] = 0.f;
    }
  }
}

extern "C" void kernel_launch(void* const* d_in, const int* in_sizes, int n_in,
                              void* d_out, int out_size, void* d_ws, size_t ws_size,
                              hipStream_t stream) {
  const float* in = (const float*)d_in[0];
  float* out = (float*)d_out;
  char* ws = (char*)d_ws;
  size_t off = 0;
  auto take = [&](size_t bytes) {
    size_t r = off;
    off += (bytes + 255) & ~(size_t)255;
    return r;
  };
  unsigned* ukey = (unsigned*)(ws + take((size_t)cB * cN * 4));
  int* topidx = (int*)(ws + take((size_t)cB * cK * 4));
  float4* boxes = (float4*)(ws + take((size_t)cB * cK * 16));
  float* area = (float*)(ws + take((size_t)cB * cK * 4));
  float* objv = (float*)(ws + take((size_t)cB * cK * 4));
  float* confv = (float*)(ws + take((size_t)cB * cK * 4));
  int* clsv = (int*)(ws + take((size_t)cB * cK * 4));
  unsigned* St = (unsigned*)(ws + take((size_t)cB * 32 * 1024 * 4));
  unsigned* cnt = (unsigned*)(ws + take((size_t)cB * 4));

  int nrows = cB * cN;
  int blocks1 = (nrows + 127) / 128;          // 128 rows per block
  k_score<<<blocks1, 256, 0, stream>>>(in, ukey);
  k_topk<<<cB, 1024, 0, stream>>>(ukey, in, topidx, boxes, area, objv, confv,
                                  clsv, cnt);
  k_suppress_nms<<<cB * 128, 256, 0, stream>>>(boxes, area, clsv, objv, confv,
                                               topidx, St, cnt, out);
}

// Round 5
// 336.944 us; speedup vs baseline: 1.2027x; 1.2027x over previous
//
#include <hip/hip_runtime.h>
#include <cstdint>

#pragma clang fp contract(off)

constexpr int cB = 16;
constexpr int cN = 22743;
constexpr int cROW = 85;
constexpr int cK = 1000;
constexpr float CONF_T = 0.5f;
constexpr float NMS_T = 0.4f;

// ---------------- kernel 1: per-row score -> orderable uint key ----------------
// Stage 128 rows into LDS coalesced; TWO threads per row, 4-accumulator ILP
// (chain depth 80 -> ~12), pair-combine via one shfl_xor. ~HBM floor (~20 us).
__global__ __launch_bounds__(256) void k_score(const float* __restrict__ in,
                                               unsigned* __restrict__ ukey) {
  __shared__ float sdata[10880];              // 128 rows x 85 floats = 43.52 KB
  constexpr int F4_PER_BLK = 2720;            // 10880 / 4
  constexpr int TOTAL_F4 = (cB * cN * cROW) / 4;
  int tid = threadIdx.x;
  const float4* gin4 = (const float4*)in;
  float4* s4 = (float4*)sdata;
  int base_f4 = blockIdx.x * F4_PER_BLK;
#pragma unroll
  for (int q = 0; q < 11; ++q) {
    int k = tid + 256 * q;
    if (k < F4_PER_BLK) {
      int g = base_f4 + k;
      if (g < TOTAL_F4) s4[k] = gin4[g];
    }
  }
  __syncthreads();
  int r = tid >> 1, h = tid & 1;              // pair (2r,2r+1) -> row r
  int grow = blockIdx.x * 128 + r;
  if (grow < cB * cN) {
    const float* rowp = sdata + cROW * r;
    int j0 = 5 + h * 40;                      // h=0: classes 0..39, h=1: 40..79
    float m0 = rowp[j0 + 0], m1 = rowp[j0 + 1];
    float m2 = rowp[j0 + 2], m3 = rowp[j0 + 3];
#pragma unroll
    for (int k = 4; k < 40; k += 4) {
      m0 = fmaxf(m0, rowp[j0 + k + 0]);
      m1 = fmaxf(m1, rowp[j0 + k + 1]);
      m2 = fmaxf(m2, rowp[j0 + k + 2]);
      m3 = fmaxf(m3, rowp[j0 + k + 3]);
    }
    float m = fmaxf(fmaxf(m0, m1), fmaxf(m2, m3));
    m = fmaxf(m, __shfl_xor(m, 1));           // partner lane = same row, other half
    if (h == 0) {
      float obj = rowp[4];
      unsigned u = 0u;
      if (obj >= CONF_T) {
        float s = obj * m;
        if (s > 0.0f) u = __float_as_uint(s);
      }
      ukey[grow] = u;
    }
  }
}

// ---------------- bitonic sort (u32 asc; only for the rare exact-tie path) ----
__device__ __forceinline__ void sort1024_u32_asc(unsigned* a, int tid) {
  for (int k = 2; k <= 1024; k <<= 1) {
    for (int j = k >> 1; j >= 1; j >>= 1) {
      __syncthreads();
      if (tid < 512) {
        int i = ((tid & ~(j - 1)) << 1) | (tid & (j - 1));
        int p = i | j;
        unsigned x = a[i], y = a[p];
        bool up = ((i & k) == 0);
        bool sw = up ? (x > y) : (x < y);
        if (sw) { a[i] = y; a[p] = x; }
      }
    }
  }
  __syncthreads();
}

// ---------------- kernel 2: exact top-1000 + GATHER fused ----------------
// Radix-select (R1 histogram form), 2-D rank split (G=8), then the former
// k_gather runs in this block's tail (R11 fusion #1 — kept; its dispatch never
// showed in top-5 and it removes a launch+gap+validv buffer).
// R12: REVERTED fusion #2 (last-block suppress+nms). R4 showed the device-scope
// threadfence x 2048 blocks costs ~145us (k_suppress_nms 150us/dispatch, HBM
// idle) — kernel boundaries are the cheap sync on this machine.
__global__ __launch_bounds__(1024) void k_topk(const unsigned* __restrict__ ukey,
                                               const float* __restrict__ in,
                                               int* __restrict__ topidx,
                                               float4* __restrict__ boxes,
                                               float* __restrict__ area,
                                               float* __restrict__ objv,
                                               float* __restrict__ confv,
                                               int* __restrict__ clsv) {
  __shared__ unsigned hist[2048];             // 8 KB
  __shared__ unsigned wtot[16];
  __shared__ unsigned long long cand[1024];   // 8 KB
  __shared__ unsigned eqbuf[1024];            // 4 KB (tie path only)
  __shared__ unsigned praw[8][1024];          // 32 KB (rank partials, G=8)
  __shared__ int sh_topidx[1024];             // 4 KB (gather phase)
  __shared__ unsigned sh_T, sh_newrank, sh_E, sh_cnt;
  int img = blockIdx.x;
  int tid = threadIdx.x;
  int lane = tid & 63;
  int wv = tid >> 6;
  const unsigned* uk = ukey + (size_t)img * cN;

  constexpr int NIT = (cN + 1023) / 1024;     // 23
  unsigned uv[NIT];
#pragma unroll
  for (int q = 0; q < NIT; ++q) {
    int i = q * 1024 + tid;
    uv[q] = (i < cN) ? uk[i] : 0u;            // 23 independent loads in flight
  }

  unsigned prefix = 0;
  int bits = 0;
  unsigned rank = cK;
  unsigned gtc = 0;   // count of keys strictly greater than current prefix block
  unsigned E = 0;     // count of keys equal to current prefix block

  for (int r = 0; r < 3; ++r) {
    int nb = (r < 2) ? 11 : 10;
    int shift = 32 - bits - nb;
    hist[tid] = 0u; hist[tid + 1024] = 0u;
    __syncthreads();
#pragma unroll
    for (int q = 0; q < NIT; ++q) {
      unsigned u = uv[q];
      bool inr = (q * 1024 + tid) < cN;
      bool match = inr && (bits == 0 || (u >> (32 - bits)) == prefix);
      bool isz = match && (u == 0u);
      bool nz = match && (u != 0u);
      // zeros all hit bin 0 -> aggregate to one atomic per wave
      unsigned long long mz = __ballot(isz);
      if (isz && lane == (__ffsll((long long)mz) - 1))
        atomicAdd(&hist[0], (unsigned)__popcll(mz));
      if (nz) atomicAdd(&hist[(u >> shift) & ((1u << nb) - 1u)], 1u);
    }
    __syncthreads();
    // hierarchical suffix scan over 2048 bins: pair-sum -> in-wave shfl suffix
    // -> 16 wave totals -> broadcast add. 3 barriers total.
    unsigned h0 = hist[2 * tid];
    unsigned h1 = hist[2 * tid + 1];
    unsigned s2 = h0 + h1;
#pragma unroll
    for (int s = 1; s < 64; s <<= 1) {
      unsigned t = __shfl_down(s2, s);
      s2 += (lane + s < 64) ? t : 0u;
    }
    if (lane == 0) wtot[wv] = s2;             // wave total (inclusive suffix at lane 0)
    __syncthreads();
    unsigned above = 0;
    for (int w2 = wv + 1; w2 < 16; ++w2) above += wtot[w2];
    unsigned S_even = above + s2;             // suffix(bin 2*tid)
    unsigned S_odd = S_even - h0;             // suffix(bin 2*tid+1)
    unsigned S_next = S_odd - h1;             // suffix(bin 2*tid+2); 0 at tid=1023
    if (S_even >= rank && S_odd < rank) { sh_T = 2u * tid; sh_newrank = rank - S_odd; sh_E = h0; }
    if (S_odd >= rank && S_next < rank) { sh_T = 2u * tid + 1u; sh_newrank = rank - S_next; sh_E = h1; }
    __syncthreads();
    unsigned T = sh_T;
    unsigned nr = sh_newrank;
    E = sh_E;
    gtc += rank - nr;
    rank = nr;
    prefix = (prefix << nb) | T;
    bits += nb;
    __syncthreads();           // hist reused next round
    if (gtc + E <= 1024u) break;
  }

  bool tiepath = (gtc + E > 1024u);   // only possible at bits==32 (exact ties)
  unsigned pivotLo = (bits >= 32) ? prefix : (prefix << (32 - bits));
  cand[tid] = (unsigned long long)tid;   // distinct filler keys, high32 = 0
  eqbuf[tid] = 0xFFFFFFFFu;
  if (tid == 0) sh_cnt = 0u;
  __syncthreads();

  if (!tiepath) {
#pragma unroll
    for (int q = 0; q < NIT; ++q) {
      int i = q * 1024 + tid;
      unsigned u = uv[q];
      bool m = (i < cN) && (u >= pivotLo);
      unsigned long long mb = __ballot(m);
      if (m) {
        int ldr = __ffsll((long long)mb) - 1;
        unsigned base = 0;
        if (lane == ldr) base = atomicAdd(&sh_cnt, (unsigned)__popcll(mb));
        base = __shfl(base, ldr);
        unsigned pos = base + (unsigned)__popcll(mb & ((1ull << lane) - 1ull));
        if (pos < 1024u)
          cand[pos] = ((unsigned long long)u << 32) |
                      (unsigned long long)(0xFFFFFFFFu - (unsigned)i);
      }
    }
    __syncthreads();
  } else {
    // exact-tie fallback: u > P into cand, u == P smallest indices appended
    unsigned P = prefix;
#pragma unroll
    for (int q = 0; q < NIT; ++q) {
      int i = q * 1024 + tid;
      unsigned u = uv[q];
      bool gt = (i < cN) && (u > P);
      unsigned long long mb = __ballot(gt);
      if (gt) {
        int ldr = __ffsll((long long)mb) - 1;
        unsigned base = 0;
        if (lane == ldr) base = atomicAdd(&sh_cnt, (unsigned)__popcll(mb));
        base = __shfl(base, ldr);
        unsigned pos = base + (unsigned)__popcll(mb & ((1ull << lane) - 1ull));
        if (pos < 1024u)
          cand[pos] = ((unsigned long long)u << 32) |
                      (unsigned long long)(0xFFFFFFFFu - (unsigned)i);
      }
    }
    __syncthreads();
    if (tid == 0) sh_E = 0u;
    __syncthreads();
#pragma unroll
    for (int q = 0; q < NIT; ++q) {
      int i = q * 1024 + tid;
      unsigned u = uv[q];
      bool eq = (i < cN) && (u == P);
      unsigned long long mb = __ballot(eq);
      if (eq) {
        int ldr = __ffsll((long long)mb) - 1;
        unsigned base = 0;
        if (lane == ldr) base = atomicAdd(&sh_E, (unsigned)__popcll(mb));
        base = __shfl(base, ldr);
        unsigned pos = base + (unsigned)__popcll(mb & ((1ull << lane) - 1ull));
        if (pos < 1024u) eqbuf[pos] = (unsigned)i;
      }
    }
    __syncthreads();
    sort1024_u32_asc(eqbuf, tid);
    int need = (int)cK - (int)gtc;
    for (int t = tid; t < need; t += 1024) {
      unsigned idx = eqbuf[t];
      if (idx != 0xFFFFFFFFu)
        cand[gtc + (unsigned)t] = ((unsigned long long)P << 32) |
                                  (unsigned long long)(0xFFFFFFFFu - idx);
    }
    __syncthreads();
  }

  // ---- rank-by-count, 2-D split, G=8 ----
  // 16 waves = 2 j-groups (jg) x 8 k-groups (kg). Lane owns 8 j's in regs.
  {
    int kg = wv & 7, jg = wv >> 3;
    unsigned long long myv[8];
#pragma unroll
    for (int m = 0; m < 8; ++m) myv[m] = cand[jg * 512 + m * 64 + lane];
    unsigned c[8];
#pragma unroll
    for (int m = 0; m < 8; ++m) c[m] = 0u;
    int k0 = kg * 128;
#pragma unroll 4
    for (int k = 0; k < 128; ++k) {
      unsigned long long ck = cand[k0 + k];   // wave-uniform broadcast read
#pragma unroll
      for (int m = 0; m < 8; ++m) c[m] += (ck > myv[m]) ? 1u : 0u;
    }
#pragma unroll
    for (int m = 0; m < 8; ++m) praw[kg][jg * 512 + m * 64 + lane] = c[m];
  }
  __syncthreads();
  unsigned rk = 0;
#pragma unroll
  for (int g = 0; g < 8; ++g) rk += praw[g][tid];
  unsigned long long my = cand[tid];
  sh_topidx[tid] = -1;
  __syncthreads();
  if (rk < (unsigned)cK) {
    unsigned uhi = (unsigned)(my >> 32);
    int idx = (int)(0xFFFFFFFFu - (unsigned)(my & 0xFFFFFFFFull));
    int oi = (uhi > 0u) ? idx : -1;
    topidx[img * cK + (int)rk] = oi;          // k_nms's valid-mask source
    sh_topidx[(int)rk] = oi;
  }
  __syncthreads();

  // ---- gather phase (former k_gather), 2 slots/wave-iter for ILP ----
  for (int j = 0; j < 32; ++j) {
    int s0 = wv + 32 * j;
    int s1 = s0 + 16;
    int i0 = (s0 < cK) ? sh_topidx[s0] : -1;
    int i1 = (s1 < cK) ? sh_topidx[s1] : -1;
    const float* r0 = in + ((size_t)img * cN + (size_t)(i0 < 0 ? 0 : i0)) * cROW;
    const float* r1 = in + ((size_t)img * cN + (size_t)(i1 < 0 ? 0 : i1)) * cROW;
    float va = r0[5 + lane];
    float vb = r1[5 + lane];
    int ca = lane, cb = lane;
    if (lane < 16) {
      float v2a = r0[69 + lane];
      float v2b = r1[69 + lane];
      if (v2a > va) { va = v2a; ca = 64 + lane; }
      if (v2b > vb) { vb = v2b; cb = 64 + lane; }
    }
#pragma unroll
    for (int m = 1; m < 64; m <<= 1) {
      float ova = __shfl_xor(va, m); int oca = __shfl_xor(ca, m);
      float ovb = __shfl_xor(vb, m); int ocb = __shfl_xor(cb, m);
      if (ova > va || (ova == va && oca < ca)) { va = ova; ca = oca; }
      if (ovb > vb || (ovb == vb && ocb < cb)) { vb = ovb; cb = ocb; }
    }
    if (lane == 0) {
      if (s0 < cK) {
        int wid = img * cK + s0;
        if (i0 < 0) {
          boxes[wid] = make_float4(0.f, 0.f, 0.f, 0.f);
          area[wid] = 0.f; objv[wid] = 0.f; confv[wid] = 0.f; clsv[wid] = -1;
        } else {
          float cx = r0[0], cy = r0[1], w = r0[2], h = r0[3], ob = r0[4];
          float hw = w * 0.5f, hh = h * 0.5f;
          float x1 = cx - hw, y1 = cy - hh, x2 = cx + hw, y2 = cy + hh;
          boxes[wid] = make_float4(x1, y1, x2, y2);
          area[wid] = fmaxf(x2 - x1, 0.f) * fmaxf(y2 - y1, 0.f);
          objv[wid] = ob; confv[wid] = va; clsv[wid] = ca;
        }
      }
      if (s1 < cK) {
        int wid = img * cK + s1;
        if (i1 < 0) {
          boxes[wid] = make_float4(0.f, 0.f, 0.f, 0.f);
          area[wid] = 0.f; objv[wid] = 0.f; confv[wid] = 0.f; clsv[wid] = -1;
        } else {
          float cx = r1[0], cy = r1[1], w = r1[2], h = r1[3], ob = r1[4];
          float hw = w * 0.5f, hh = h * 0.5f;
          float x1 = cx - hw, y1 = cy - hh, x2 = cx + hw, y2 = cy + hh;
          boxes[wid] = make_float4(x1, y1, x2, y2);
          area[wid] = fmaxf(x2 - x1, 0.f) * fmaxf(y2 - y1, 0.f);
          objv[wid] = ob; confv[wid] = vb; clsv[wid] = cb;
        }
      }
    }
  }
}

// ---------------- kernel 3: suppress bitmask, TRANSPOSED output ----------------
// St[img][w][i] (i padded to 1024): word w of suppress-row i. (R3 form.)
__global__ __launch_bounds__(256) void k_suppress(const float4* __restrict__ boxes,
                                                  const float* __restrict__ area,
                                                  const int* __restrict__ clsv,
                                                  unsigned* __restrict__ St) {
  // +(i>>5) padding: inner-loop bank = (w+bit)%32 -> conflict-free
  __shared__ float sx1[1056], sy1[1056], sx2[1056], sy2[1056], sar[1056];
  __shared__ int scls[1056];
  int img = blockIdx.x >> 7;            // / 128
  int rb = (blockIdx.x & 127) * 8;      // 128 blocks x 8 rows = 1024 rows
  int tid = threadIdx.x;
  for (int i = tid; i < 1024; i += 256) {
    int p = i + (i >> 5);
    if (i < cK) {
      float4 b = boxes[img * cK + i];
      sx1[p] = b.x; sy1[p] = b.y; sx2[p] = b.z; sy2[p] = b.w;
      sar[p] = area[img * cK + i];
      scls[p] = clsv[img * cK + i];
    } else {
      sx1[p] = 0.f; sy1[p] = 0.f; sx2[p] = 0.f; sy2[p] = 0.f; sar[p] = 0.f;
      scls[p] = -2;
    }
  }
  __syncthreads();
  int i = rb + (tid >> 5);
  int w = tid & 31;
  int pi = i + (i >> 5);
  float bx1 = sx1[pi], by1 = sy1[pi], bx2 = sx2[pi], by2 = sy2[pi], ba = sar[pi];
  int bc = scls[pi];
  unsigned word = 0u;
#pragma unroll 4
  for (int bit = 0; bit < 32; ++bit) {
    int pj = 33 * w + bit;
    float xx1 = fmaxf(bx1, sx1[pj]);
    float yy1 = fmaxf(by1, sy1[pj]);
    float xx2 = fminf(bx2, sx2[pj]);
    float yy2 = fminf(by2, sy2[pj]);
    float inter = fmaxf(xx2 - xx1, 0.f) * fmaxf(yy2 - yy1, 0.f);
    float uni = ba + sar[pj] - inter;
    float iou = inter / (uni + 1e-16f);
    if (iou > NMS_T && bc == scls[pj]) word |= (1u << bit);
  }
  St[((size_t)(img * 32 + w)) * 1024 + (size_t)i] = word;
}

// ---------------- kernel 4: word-batched greedy NMS + masked write ----------------
// All buffer accesses use compile-time indices (no runtime-selected pointer) so
// bufA/bufB stay in VGPRs.
__device__ __forceinline__ unsigned u4c(const uint4& v, int c) {
  return c == 0 ? v.x : c == 1 ? v.y : c == 2 ? v.z : v.w;
}

__device__ __forceinline__ void nms_load(const uint4* __restrict__ colv, int b,
                                         uint4 (&buf)[8]) {
#pragma unroll
  for (int q = 0; q < 8; ++q) buf[q] = colv[8 * b + q];
}

__device__ __forceinline__ void nms_proc(int b, int lane, unsigned& kw,
                                         const uint4 (&W)[8]) {
  unsigned dec = 0u;
  if (lane == b) {
    unsigned kwb = kw;
#pragma unroll
    for (int t = 0; t < 32; ++t) {
      if ((kwb >> t) & 1u) {
        dec |= (1u << t);
        unsigned rw = u4c(W[t >> 2], t & 3);
        unsigned mgt = (t == 31) ? 0u : (0xFFFFFFFFu << (t + 1));
        kwb &= ~(rw & mgt);   // kill only later rows within this word
      }
    }
    kw = kwb;
  }
  dec = __shfl(dec, b);       // broadcast the 32 decisions
  if (dec != 0u && lane > b) {   // skip apply when no kept rows in word b
#pragma unroll
    for (int t = 0; t < 32; ++t) {
      unsigned sel = 0u - ((dec >> t) & 1u);
      kw &= ~(u4c(W[t >> 2], t & 3) & sel);
    }
  }
}

__global__ __launch_bounds__(64) void k_nms(const unsigned* __restrict__ St,
                                            const int* __restrict__ topidx,
                                            const float4* __restrict__ boxes,
                                            const float* __restrict__ objv,
                                            const float* __restrict__ confv,
                                            const int* __restrict__ clsv,
                                            float* __restrict__ out) {
  __shared__ unsigned keep_sh[32];
  int img = blockIdx.x;
  int lane = threadIdx.x;
  if (lane < 32) {
    const uint4* colv = (const uint4*)(St + ((size_t)(img * 32 + lane)) * 1024);
    // valid mask from 8 coalesced int4 loads of topidx (>=0 means valid)
    unsigned kw = 0u;
    const int4* v4 = (const int4*)(topidx + img * cK);
#pragma unroll
    for (int q = 0; q < 8; ++q) {
      int k0 = (lane << 5) + 4 * q;
      if (k0 < cK) {
        int4 t = v4[lane * 8 + q];
        kw |= (unsigned)(t.x >= 0) << (4 * q + 0);
        kw |= (unsigned)(t.y >= 0) << (4 * q + 1);
        kw |= (unsigned)(t.z >= 0) << (4 * q + 2);
        kw |= (unsigned)(t.w >= 0) << (4 * q + 3);
      }
    }
    uint4 bufA[8], bufB[8];
    nms_load(colv, 0, bufA);
    for (int b = 0; b < 32; b += 2) {
      if (b + 1 < 32) nms_load(colv, b + 1, bufB);
      nms_proc(b, lane, kw, bufA);
      if (b + 2 < 32) nms_load(colv, b + 2, bufA);
      nms_proc(b + 1, lane, kw, bufB);
    }
    keep_sh[lane] = kw;
  }
  __syncthreads();
  for (int k = lane; k < cK; k += 64) {
    bool kp = ((keep_sh[k >> 5] >> (k & 31)) & 1u) != 0u;
    size_t o = ((size_t)img * cK + (size_t)k) * 7;
    if (kp) {
      float4 b = boxes[img * cK + k];
      out[o + 0] = b.x; out[o + 1] = b.y; out[o + 2] = b.z; out[o + 3] = b.w;
      out[o + 4] = objv[img * cK + k];
      out[o + 5] = confv[img * cK + k];
      out[o + 6] = (float)clsv[img * cK + k];
    } else {
      out[o + 0] = 0.f; out[o + 1] = 0.f; out[o + 2] = 0.f; out[o + 3] = 0.f;
      out[o + 4] = 0.f; out[o + 5] = 0.f; out[o + 6] = 0.f;
    }
  }
}

extern "C" void kernel_launch(void* const* d_in, const int* in_sizes, int n_in,
                              void* d_out, int out_size, void* d_ws, size_t ws_size,
                              hipStream_t stream) {
  const float* in = (const float*)d_in[0];
  float* out = (float*)d_out;
  char* ws = (char*)d_ws;
  size_t off = 0;
  auto take = [&](size_t bytes) {
    size_t r = off;
    off += (bytes + 255) & ~(size_t)255;
    return r;
  };
  unsigned* ukey = (unsigned*)(ws + take((size_t)cB * cN * 4));
  int* topidx = (int*)(ws + take((size_t)cB * cK * 4));
  float4* boxes = (float4*)(ws + take((size_t)cB * cK * 16));
  float* area = (float*)(ws + take((size_t)cB * cK * 4));
  float* objv = (float*)(ws + take((size_t)cB * cK * 4));
  float* confv = (float*)(ws + take((size_t)cB * cK * 4));
  int* clsv = (int*)(ws + take((size_t)cB * cK * 4));
  unsigned* St = (unsigned*)(ws + take((size_t)cB * 32 * 1024 * 4));

  int nrows = cB * cN;
  int blocks1 = (nrows + 127) / 128;          // 128 rows per block
  k_score<<<blocks1, 256, 0, stream>>>(in, ukey);
  k_topk<<<cB, 1024, 0, stream>>>(ukey, in, topidx, boxes, area, objv, confv,
                                  clsv);
  k_suppress<<<cB * 128, 256, 0, stream>>>(boxes, area, clsv, St);
  k_nms<<<cB, 64, 0, stream>>>(St, topidx, boxes, objv, confv, clsv, out);
}

// Round 6
// 282.068 us; speedup vs baseline: 1.4367x; 1.1946x over previous
//
#include <hip/hip_runtime.h>
#include <cstdint>

#pragma clang fp contract(off)

constexpr int cB = 16;
constexpr int cN = 22743;
constexpr int cNP = 23552;   // 23*1024 padded key stride (uint4-aligned staging)
constexpr int cROW = 85;
constexpr int cK = 1000;
constexpr float CONF_T = 0.5f;
constexpr float NMS_T = 0.4f;

// ---------------- kernel 1: per-row score -> orderable uint key ----------------
// Stage 128 rows into LDS coalesced; TWO threads per row, 4-accumulator ILP,
// pair-combine via one shfl_xor. ~HBM floor (~20-25 us).
// R13: ukey written with padded stride cNP so k_topk can uint4-stage it.
__global__ __launch_bounds__(256) void k_score(const float* __restrict__ in,
                                               unsigned* __restrict__ ukey) {
  __shared__ float sdata[10880];              // 128 rows x 85 floats = 43.52 KB
  constexpr int F4_PER_BLK = 2720;            // 10880 / 4
  constexpr int TOTAL_F4 = (cB * cN * cROW) / 4;
  int tid = threadIdx.x;
  const float4* gin4 = (const float4*)in;
  float4* s4 = (float4*)sdata;
  int base_f4 = blockIdx.x * F4_PER_BLK;
#pragma unroll
  for (int q = 0; q < 11; ++q) {
    int k = tid + 256 * q;
    if (k < F4_PER_BLK) {
      int g = base_f4 + k;
      if (g < TOTAL_F4) s4[k] = gin4[g];
    }
  }
  __syncthreads();
  int r = tid >> 1, h = tid & 1;              // pair (2r,2r+1) -> row r
  int grow = blockIdx.x * 128 + r;
  if (grow < cB * cN) {
    const float* rowp = sdata + cROW * r;
    int j0 = 5 + h * 40;                      // h=0: classes 0..39, h=1: 40..79
    float m0 = rowp[j0 + 0], m1 = rowp[j0 + 1];
    float m2 = rowp[j0 + 2], m3 = rowp[j0 + 3];
#pragma unroll
    for (int k = 4; k < 40; k += 4) {
      m0 = fmaxf(m0, rowp[j0 + k + 0]);
      m1 = fmaxf(m1, rowp[j0 + k + 1]);
      m2 = fmaxf(m2, rowp[j0 + k + 2]);
      m3 = fmaxf(m3, rowp[j0 + k + 3]);
    }
    float m = fmaxf(fmaxf(m0, m1), fmaxf(m2, m3));
    m = fmaxf(m, __shfl_xor(m, 1));           // partner lane = same row, other half
    if (h == 0) {
      float obj = rowp[4];
      unsigned u = 0u;
      if (obj >= CONF_T) {
        float s = obj * m;
        if (s > 0.0f) u = __float_as_uint(s);
      }
      int im = grow / cN;                     // const-divisor -> magic mul
      int n = grow - im * cN;
      ukey[im * cNP + n] = u;
    }
  }
}

// ---------------- bitonic sort (u32 asc; only for the rare exact-tie path) ----
__device__ __forceinline__ void sort1024_u32_asc(unsigned* a, int tid) {
  for (int k = 2; k <= 1024; k <<= 1) {
    for (int j = k >> 1; j >= 1; j >>= 1) {
      __syncthreads();
      if (tid < 512) {
        int i = ((tid & ~(j - 1)) << 1) | (tid & (j - 1));
        int p = i | j;
        unsigned x = a[i], y = a[p];
        bool up = ((i & k) == 0);
        bool sw = up ? (x > y) : (x < y);
        if (sw) { a[i] = y; a[p] = x; }
      }
    }
  }
  __syncthreads();
}

// ---------------- kernel 2: exact top-1000 per image ----------------
// R13: ALL phases read keys from a one-shot LDS stage (skey, 94 KB) instead of
// register-resident uv[23] (R5: VGPR_Count=44 -> compiler wasn't keeping them;
// phases were latency-bound on reloads). grid=16 so the 128 KB LDS footprint
// costs nothing. Gather is back to its own 4000-block kernel (R5 counters:
// in-block gather = ~67 us of serial latency on 16 CUs vs ~5 us standalone).
__global__ __launch_bounds__(1024) void k_topk(const unsigned* __restrict__ ukey,
                                               int* __restrict__ topidx) {
  __shared__ unsigned skey[cNP];              // 94.2 KB
  __shared__ unsigned hist[2048];             // 8 KB
  __shared__ unsigned wtot[16];
  __shared__ unsigned long long cand[1024];   // 8 KB
  __shared__ unsigned eqbuf[1024];            // 4 KB (tie path only)
  __shared__ unsigned praw[4][1024];          // 16 KB (rank partials)
  __shared__ unsigned sh_T, sh_newrank, sh_E, sh_cnt;
  int img = blockIdx.x;
  int tid = threadIdx.x;
  int lane = tid & 63;
  int wv = tid >> 6;
  const unsigned* uk = ukey + (size_t)img * cNP;

  // ---- stage keys to LDS: 5685 full uint4 (keys 0..22739), then scalar tail
  // 22740..22742 and zero-pad 22743..23551 (no write-write races).
  {
    const uint4* uk4 = (const uint4*)uk;
    uint4* sk4 = (uint4*)skey;
#pragma unroll
    for (int q = 0; q < 6; ++q) {
      int i4 = q * 1024 + tid;
      if (i4 < 5685) sk4[i4] = uk4[i4];
    }
    int i = 22740 + tid;
    if (i < cNP) skey[i] = (i < cN) ? uk[i] : 0u;
  }
  __syncthreads();

  constexpr int NIT = cNP / 1024;             // 23
  unsigned prefix = 0;
  int bits = 0;
  unsigned rank = cK;
  unsigned gtc = 0;   // count of keys strictly greater than current prefix block
  unsigned E = 0;     // count of keys equal to current prefix block

  for (int r = 0; r < 3; ++r) {
    int nb = (r < 2) ? 11 : 10;
    int shift = 32 - bits - nb;
    hist[tid] = 0u; hist[tid + 1024] = 0u;
    __syncthreads();
#pragma unroll
    for (int q = 0; q < NIT; ++q) {
      int i = q * 1024 + tid;
      unsigned u = skey[i];
      bool inr = i < cN;
      bool match = inr && (bits == 0 || (u >> (32 - bits)) == prefix);
      bool isz = match && (u == 0u);
      bool nz = match && (u != 0u);
      // zeros all hit bin 0 -> aggregate to one atomic per wave
      unsigned long long mz = __ballot(isz);
      if (isz && lane == (__ffsll((long long)mz) - 1))
        atomicAdd(&hist[0], (unsigned)__popcll(mz));
      if (nz) atomicAdd(&hist[(u >> shift) & ((1u << nb) - 1u)], 1u);
    }
    __syncthreads();
    // hierarchical suffix scan over 2048 bins: pair-sum -> in-wave shfl suffix
    // -> 16 wave totals -> broadcast add. 3 barriers total.
    unsigned h0 = hist[2 * tid];
    unsigned h1 = hist[2 * tid + 1];
    unsigned s2 = h0 + h1;
#pragma unroll
    for (int s = 1; s < 64; s <<= 1) {
      unsigned t = __shfl_down(s2, s);
      s2 += (lane + s < 64) ? t : 0u;
    }
    if (lane == 0) wtot[wv] = s2;             // wave total (inclusive suffix at lane 0)
    __syncthreads();
    unsigned above = 0;
    for (int w2 = wv + 1; w2 < 16; ++w2) above += wtot[w2];
    unsigned S_even = above + s2;             // suffix(bin 2*tid)
    unsigned S_odd = S_even - h0;             // suffix(bin 2*tid+1)
    unsigned S_next = S_odd - h1;             // suffix(bin 2*tid+2); 0 at tid=1023
    if (S_even >= rank && S_odd < rank) { sh_T = 2u * tid; sh_newrank = rank - S_odd; sh_E = h0; }
    if (S_odd >= rank && S_next < rank) { sh_T = 2u * tid + 1u; sh_newrank = rank - S_next; sh_E = h1; }
    __syncthreads();
    unsigned T = sh_T;
    unsigned nr = sh_newrank;
    E = sh_E;
    gtc += rank - nr;
    rank = nr;
    prefix = (prefix << nb) | T;
    bits += nb;
    __syncthreads();           // hist reused next round
    if (gtc + E <= 1024u) break;
  }

  bool tiepath = (gtc + E > 1024u);   // only possible at bits==32 (exact ties)
  unsigned pivotLo = (bits >= 32) ? prefix : (prefix << (32 - bits));
  cand[tid] = (unsigned long long)tid;   // distinct filler keys, high32 = 0
  eqbuf[tid] = 0xFFFFFFFFu;
  if (tid == 0) sh_cnt = 0u;
  __syncthreads();

  if (!tiepath) {
#pragma unroll
    for (int q = 0; q < NIT; ++q) {
      int i = q * 1024 + tid;
      unsigned u = skey[i];
      bool m = (i < cN) && (u >= pivotLo);
      unsigned long long mb = __ballot(m);
      if (m) {
        int ldr = __ffsll((long long)mb) - 1;
        unsigned base = 0;
        if (lane == ldr) base = atomicAdd(&sh_cnt, (unsigned)__popcll(mb));
        base = __shfl(base, ldr);
        unsigned pos = base + (unsigned)__popcll(mb & ((1ull << lane) - 1ull));
        if (pos < 1024u)
          cand[pos] = ((unsigned long long)u << 32) |
                      (unsigned long long)(0xFFFFFFFFu - (unsigned)i);
      }
    }
    __syncthreads();
  } else {
    // exact-tie fallback: u > P into cand, u == P smallest indices appended
    unsigned P = prefix;
#pragma unroll
    for (int q = 0; q < NIT; ++q) {
      int i = q * 1024 + tid;
      unsigned u = skey[i];
      bool gt = (i < cN) && (u > P);
      unsigned long long mb = __ballot(gt);
      if (gt) {
        int ldr = __ffsll((long long)mb) - 1;
        unsigned base = 0;
        if (lane == ldr) base = atomicAdd(&sh_cnt, (unsigned)__popcll(mb));
        base = __shfl(base, ldr);
        unsigned pos = base + (unsigned)__popcll(mb & ((1ull << lane) - 1ull));
        if (pos < 1024u)
          cand[pos] = ((unsigned long long)u << 32) |
                      (unsigned long long)(0xFFFFFFFFu - (unsigned)i);
      }
    }
    __syncthreads();
    if (tid == 0) sh_E = 0u;
    __syncthreads();
#pragma unroll
    for (int q = 0; q < NIT; ++q) {
      int i = q * 1024 + tid;
      unsigned u = skey[i];
      bool eq = (i < cN) && (u == P);
      unsigned long long mb = __ballot(eq);
      if (eq) {
        int ldr = __ffsll((long long)mb) - 1;
        unsigned base = 0;
        if (lane == ldr) base = atomicAdd(&sh_E, (unsigned)__popcll(mb));
        base = __shfl(base, ldr);
        unsigned pos = base + (unsigned)__popcll(mb & ((1ull << lane) - 1ull));
        if (pos < 1024u) eqbuf[pos] = (unsigned)i;
      }
    }
    __syncthreads();
    sort1024_u32_asc(eqbuf, tid);
    int need = (int)cK - (int)gtc;
    for (int t = tid; t < need; t += 1024) {
      unsigned idx = eqbuf[t];
      if (idx != 0xFFFFFFFFu)
        cand[gtc + (unsigned)t] = ((unsigned long long)P << 32) |
                                  (unsigned long long)(0xFFFFFFFFu - idx);
    }
    __syncthreads();
  }

  // ---- rank-by-count, 2-D split (R10): 4 j-groups x 4 k-groups ----
  {
    int jg = wv & 3, kg = wv >> 2;
    unsigned long long myv0 = cand[jg * 256 + 0 * 64 + lane];
    unsigned long long myv1 = cand[jg * 256 + 1 * 64 + lane];
    unsigned long long myv2 = cand[jg * 256 + 2 * 64 + lane];
    unsigned long long myv3 = cand[jg * 256 + 3 * 64 + lane];
    unsigned c0 = 0, c1 = 0, c2 = 0, c3 = 0;
    int k0 = kg * 256;
#pragma unroll 4
    for (int k = 0; k < 256; ++k) {
      unsigned long long ck = cand[k0 + k];   // wave-uniform broadcast read
      c0 += (ck > myv0) ? 1u : 0u;
      c1 += (ck > myv1) ? 1u : 0u;
      c2 += (ck > myv2) ? 1u : 0u;
      c3 += (ck > myv3) ? 1u : 0u;
    }
    praw[kg][jg * 256 + 0 * 64 + lane] = c0;
    praw[kg][jg * 256 + 1 * 64 + lane] = c1;
    praw[kg][jg * 256 + 2 * 64 + lane] = c2;
    praw[kg][jg * 256 + 3 * 64 + lane] = c3;
  }
  __syncthreads();
  unsigned rk = praw[0][tid] + praw[1][tid] + praw[2][tid] + praw[3][tid];
  unsigned long long my = cand[tid];
  if (rk < (unsigned)cK) {
    unsigned uhi = (unsigned)(my >> 32);
    int idx = (int)(0xFFFFFFFFu - (unsigned)(my & 0xFFFFFFFFull));
    topidx[img * cK + (int)rk] = (uhi > 0u) ? idx : -1;
  }
}

// ---------------- kernel 3: gather (standalone again, 4000 blocks) ----------
__global__ __launch_bounds__(256) void k_gather(const float* __restrict__ in,
                                                const int* __restrict__ topidx,
                                                float4* __restrict__ boxes,
                                                float* __restrict__ area,
                                                float* __restrict__ objv,
                                                float* __restrict__ confv,
                                                int* __restrict__ clsv) {
  int wid = (int)((blockIdx.x * 256u + threadIdx.x) >> 6);
  int lane = threadIdx.x & 63;
  if (wid >= cB * cK) return;
  int img = wid / cK;
  int idx = topidx[wid];
  if (idx < 0) {
    if (lane == 0) {
      boxes[wid] = make_float4(0.f, 0.f, 0.f, 0.f);
      area[wid] = 0.f; objv[wid] = 0.f; confv[wid] = 0.f;
      clsv[wid] = -1;
    }
    return;
  }
  const float* row = in + ((size_t)img * cN + (size_t)idx) * cROW;
  float v = row[5 + lane];
  int ci = lane;
  if (lane < 16) {
    float v2 = row[69 + lane];
    if (v2 > v) { v = v2; ci = 64 + lane; }
  }
#pragma unroll
  for (int m = 1; m < 64; m <<= 1) {
    float ov = __shfl_xor(v, m);
    int oc = __shfl_xor(ci, m);
    if (ov > v || (ov == v && oc < ci)) { v = ov; ci = oc; }
  }
  if (lane == 0) {
    float cx = row[0], cy = row[1], w = row[2], h = row[3], ob = row[4];
    float hw = w * 0.5f, hh = h * 0.5f;
    float x1 = cx - hw, y1 = cy - hh, x2 = cx + hw, y2 = cy + hh;
    boxes[wid] = make_float4(x1, y1, x2, y2);
    area[wid] = fmaxf(x2 - x1, 0.f) * fmaxf(y2 - y1, 0.f);
    objv[wid] = ob; confv[wid] = v; clsv[wid] = ci;
  }
}

// ---------------- kernel 4: suppress bitmask, TRANSPOSED output ----------------
// St[img][w][i] (i padded to 1024): word w of suppress-row i.
__global__ __launch_bounds__(256) void k_suppress(const float4* __restrict__ boxes,
                                                  const float* __restrict__ area,
                                                  const int* __restrict__ clsv,
                                                  unsigned* __restrict__ St) {
  // +(i>>5) padding: inner-loop bank = (w+bit)%32 -> conflict-free
  __shared__ float sx1[1056], sy1[1056], sx2[1056], sy2[1056], sar[1056];
  __shared__ int scls[1056];
  int img = blockIdx.x >> 7;            // / 128
  int rb = (blockIdx.x & 127) * 8;      // 128 blocks x 8 rows = 1024 rows
  int tid = threadIdx.x;
  for (int i = tid; i < 1024; i += 256) {
    int p = i + (i >> 5);
    if (i < cK) {
      float4 b = boxes[img * cK + i];
      sx1[p] = b.x; sy1[p] = b.y; sx2[p] = b.z; sy2[p] = b.w;
      sar[p] = area[img * cK + i];
      scls[p] = clsv[img * cK + i];
    } else {
      sx1[p] = 0.f; sy1[p] = 0.f; sx2[p] = 0.f; sy2[p] = 0.f; sar[p] = 0.f;
      scls[p] = -2;
    }
  }
  __syncthreads();
  int i = rb + (tid >> 5);
  int w = tid & 31;
  int pi = i + (i >> 5);
  float bx1 = sx1[pi], by1 = sy1[pi], bx2 = sx2[pi], by2 = sy2[pi], ba = sar[pi];
  int bc = scls[pi];
  unsigned word = 0u;
#pragma unroll 4
  for (int bit = 0; bit < 32; ++bit) {
    int pj = 33 * w + bit;
    float xx1 = fmaxf(bx1, sx1[pj]);
    float yy1 = fmaxf(by1, sy1[pj]);
    float xx2 = fminf(bx2, sx2[pj]);
    float yy2 = fminf(by2, sy2[pj]);
    float inter = fmaxf(xx2 - xx1, 0.f) * fmaxf(yy2 - yy1, 0.f);
    float uni = ba + sar[pj] - inter;
    float iou = inter / (uni + 1e-16f);
    if (iou > NMS_T && bc == scls[pj]) word |= (1u << bit);
  }
  St[((size_t)(img * 32 + w)) * 1024 + (size_t)i] = word;
}

// ---------------- kernel 5: word-batched greedy NMS + masked write ----------------
__device__ __forceinline__ unsigned u4c(const uint4& v, int c) {
  return c == 0 ? v.x : c == 1 ? v.y : c == 2 ? v.z : v.w;
}

__device__ __forceinline__ void nms_load(const uint4* __restrict__ colv, int b,
                                         uint4 (&buf)[8]) {
#pragma unroll
  for (int q = 0; q < 8; ++q) buf[q] = colv[8 * b + q];
}

__device__ __forceinline__ void nms_proc(int b, int lane, unsigned& kw,
                                         const uint4 (&W)[8]) {
  unsigned dec = 0u;
  if (lane == b) {
    unsigned kwb = kw;
#pragma unroll
    for (int t = 0; t < 32; ++t) {
      if ((kwb >> t) & 1u) {
        dec |= (1u << t);
        unsigned rw = u4c(W[t >> 2], t & 3);
        unsigned mgt = (t == 31) ? 0u : (0xFFFFFFFFu << (t + 1));
        kwb &= ~(rw & mgt);   // kill only later rows within this word
      }
    }
    kw = kwb;
  }
  dec = __shfl(dec, b);       // broadcast the 32 decisions
  if (dec != 0u && lane > b) {   // skip apply when no kept rows in word b
#pragma unroll
    for (int t = 0; t < 32; ++t) {
      unsigned sel = 0u - ((dec >> t) & 1u);
      kw &= ~(u4c(W[t >> 2], t & 3) & sel);
    }
  }
}

__global__ __launch_bounds__(64) void k_nms(const unsigned* __restrict__ St,
                                            const int* __restrict__ topidx,
                                            const float4* __restrict__ boxes,
                                            const float* __restrict__ objv,
                                            const float* __restrict__ confv,
                                            const int* __restrict__ clsv,
                                            float* __restrict__ out) {
  __shared__ unsigned keep_sh[32];
  int img = blockIdx.x;
  int lane = threadIdx.x;
  if (lane < 32) {
    const uint4* colv = (const uint4*)(St + ((size_t)(img * 32 + lane)) * 1024);
    // valid mask from 8 coalesced int4 loads of topidx (>=0 means valid)
    unsigned kw = 0u;
    const int4* v4 = (const int4*)(topidx + img * cK);
#pragma unroll
    for (int q = 0; q < 8; ++q) {
      int k0 = (lane << 5) + 4 * q;
      if (k0 < cK) {
        int4 t = v4[lane * 8 + q];
        kw |= (unsigned)(t.x >= 0) << (4 * q + 0);
        kw |= (unsigned)(t.y >= 0) << (4 * q + 1);
        kw |= (unsigned)(t.z >= 0) << (4 * q + 2);
        kw |= (unsigned)(t.w >= 0) << (4 * q + 3);
      }
    }
    uint4 bufA[8], bufB[8];
    nms_load(colv, 0, bufA);
    for (int b = 0; b < 32; b += 2) {
      if (b + 1 < 32) nms_load(colv, b + 1, bufB);
      nms_proc(b, lane, kw, bufA);
      if (b + 2 < 32) nms_load(colv, b + 2, bufA);
      nms_proc(b + 1, lane, kw, bufB);
    }
    keep_sh[lane] = kw;
  }
  __syncthreads();
  for (int k = lane; k < cK; k += 64) {
    bool kp = ((keep_sh[k >> 5] >> (k & 31)) & 1u) != 0u;
    size_t o = ((size_t)img * cK + (size_t)k) * 7;
    if (kp) {
      float4 b = boxes[img * cK + k];
      out[o + 0] = b.x; out[o + 1] = b.y; out[o + 2] = b.z; out[o + 3] = b.w;
      out[o + 4] = objv[img * cK + k];
      out[o + 5] = confv[img * cK + k];
      out[o + 6] = (float)clsv[img * cK + k];
    } else {
      out[o + 0] = 0.f; out[o + 1] = 0.f; out[o + 2] = 0.f; out[o + 3] = 0.f;
      out[o + 4] = 0.f; out[o + 5] = 0.f; out[o + 6] = 0.f;
    }
  }
}

extern "C" void kernel_launch(void* const* d_in, const int* in_sizes, int n_in,
                              void* d_out, int out_size, void* d_ws, size_t ws_size,
                              hipStream_t stream) {
  const float* in = (const float*)d_in[0];
  float* out = (float*)d_out;
  char* ws = (char*)d_ws;
  size_t off = 0;
  auto take = [&](size_t bytes) {
    size_t r = off;
    off += (bytes + 255) & ~(size_t)255;
    return r;
  };
  unsigned* ukey = (unsigned*)(ws + take((size_t)cB * cNP * 4));
  int* topidx = (int*)(ws + take((size_t)cB * cK * 4));
  float4* boxes = (float4*)(ws + take((size_t)cB * cK * 16));
  float* area = (float*)(ws + take((size_t)cB * cK * 4));
  float* objv = (float*)(ws + take((size_t)cB * cK * 4));
  float* confv = (float*)(ws + take((size_t)cB * cK * 4));
  int* clsv = (int*)(ws + take((size_t)cB * cK * 4));
  unsigned* St = (unsigned*)(ws + take((size_t)cB * 32 * 1024 * 4));

  int nrows = cB * cN;
  int blocks1 = (nrows + 127) / 128;          // 128 rows per block
  k_score<<<blocks1, 256, 0, stream>>>(in, ukey);
  k_topk<<<cB, 1024, 0, stream>>>(ukey, topidx);
  int waves3 = cB * cK;
  k_gather<<<(waves3 * 64 + 255) / 256, 256, 0, stream>>>(in, topidx, boxes, area,
                                                          objv, confv, clsv);
  k_suppress<<<cB * 128, 256, 0, stream>>>(boxes, area, clsv, St);
  k_nms<<<cB, 64, 0, stream>>>(St, topidx, boxes, objv, confv, clsv, out);
}

// Round 7
// 276.588 us; speedup vs baseline: 1.4651x; 1.0198x over previous
//
#include <hip/hip_runtime.h>
#include <cstdint>

#pragma clang fp contract(off)

constexpr int cB = 16;
constexpr int cN = 22743;
constexpr int cROW = 85;
constexpr int cK = 1000;
constexpr float CONF_T = 0.5f;
constexpr float NMS_T = 0.4f;

// ---------------- kernel 1: per-row score -> orderable uint key ----------------
// Stage 128 rows into LDS coalesced; TWO threads per row, 4-accumulator ILP,
// pair-combine via one shfl_xor. ~HBM floor (124 MB mandatory read ~20 us).
__global__ __launch_bounds__(256) void k_score(const float* __restrict__ in,
                                               unsigned* __restrict__ ukey) {
  __shared__ float sdata[10880];              // 128 rows x 85 floats = 43.52 KB
  constexpr int F4_PER_BLK = 2720;            // 10880 / 4
  constexpr int TOTAL_F4 = (cB * cN * cROW) / 4;
  int tid = threadIdx.x;
  const float4* gin4 = (const float4*)in;
  float4* s4 = (float4*)sdata;
  int base_f4 = blockIdx.x * F4_PER_BLK;
#pragma unroll
  for (int q = 0; q < 11; ++q) {
    int k = tid + 256 * q;
    if (k < F4_PER_BLK) {
      int g = base_f4 + k;
      if (g < TOTAL_F4) s4[k] = gin4[g];
    }
  }
  __syncthreads();
  int r = tid >> 1, h = tid & 1;              // pair (2r,2r+1) -> row r
  int grow = blockIdx.x * 128 + r;
  if (grow < cB * cN) {
    const float* rowp = sdata + cROW * r;
    int j0 = 5 + h * 40;                      // h=0: classes 0..39, h=1: 40..79
    float m0 = rowp[j0 + 0], m1 = rowp[j0 + 1];
    float m2 = rowp[j0 + 2], m3 = rowp[j0 + 3];
#pragma unroll
    for (int k = 4; k < 40; k += 4) {
      m0 = fmaxf(m0, rowp[j0 + k + 0]);
      m1 = fmaxf(m1, rowp[j0 + k + 1]);
      m2 = fmaxf(m2, rowp[j0 + k + 2]);
      m3 = fmaxf(m3, rowp[j0 + k + 3]);
    }
    float m = fmaxf(fmaxf(m0, m1), fmaxf(m2, m3));
    m = fmaxf(m, __shfl_xor(m, 1));           // partner lane = same row, other half
    if (h == 0) {
      float obj = rowp[4];
      unsigned u = 0u;
      if (obj >= CONF_T) {
        float s = obj * m;
        if (s > 0.0f) u = __float_as_uint(s);
      }
      ukey[grow] = u;
    }
  }
}

// ---------------- bitonic sort (u32 asc; only for the rare exact-tie path) ----
__device__ __forceinline__ void sort1024_u32_asc(unsigned* a, int tid) {
  for (int k = 2; k <= 1024; k <<= 1) {
    for (int j = k >> 1; j >= 1; j >>= 1) {
      __syncthreads();
      if (tid < 512) {
        int i = ((tid & ~(j - 1)) << 1) | (tid & (j - 1));
        int p = i | j;
        unsigned x = a[i], y = a[p];
        bool up = ((i & k) == 0);
        bool sw = up ? (x > y) : (x < y);
        if (sw) { a[i] = y; a[p] = x; }
      }
    }
  }
  __syncthreads();
}

// ---------------- kernel 2: exact top-1000 per image (R3 form = best measured) -
// 11-bit histogram radix-select, keys register-resident uv[23] (R8), zeros-
// aggregated per-lane LDS atomics (R2 match-any regressed; same-address LDS
// atomicAdd is cheap), hierarchical 3-barrier scan, compaction, 2-D G=4
// rank-by-count (R10). R6's LDS key staging was neutral -> reverted to this.
__global__ __launch_bounds__(1024) void k_topk(const unsigned* __restrict__ ukey,
                                               int* __restrict__ topidx) {
  __shared__ unsigned hist[2048];             // 8 KB
  __shared__ unsigned wtot[16];
  __shared__ unsigned long long cand[1024];   // 8 KB
  __shared__ unsigned eqbuf[1024];            // 4 KB (tie path only)
  __shared__ unsigned praw[4][1024];          // 16 KB (rank partials)
  __shared__ unsigned sh_T, sh_newrank, sh_E, sh_cnt;
  int img = blockIdx.x;
  int tid = threadIdx.x;
  int lane = tid & 63;
  int wv = tid >> 6;
  const unsigned* uk = ukey + (size_t)img * cN;

  constexpr int NIT = (cN + 1023) / 1024;     // 23
  unsigned uv[NIT];
#pragma unroll
  for (int q = 0; q < NIT; ++q) {
    int i = q * 1024 + tid;
    uv[q] = (i < cN) ? uk[i] : 0u;            // 23 independent loads in flight
  }

  unsigned prefix = 0;
  int bits = 0;
  unsigned rank = cK;
  unsigned gtc = 0;   // count of keys strictly greater than current prefix block
  unsigned E = 0;     // count of keys equal to current prefix block

  for (int r = 0; r < 3; ++r) {
    int nb = (r < 2) ? 11 : 10;
    int shift = 32 - bits - nb;
    hist[tid] = 0u; hist[tid + 1024] = 0u;
    __syncthreads();
#pragma unroll
    for (int q = 0; q < NIT; ++q) {
      unsigned u = uv[q];
      bool inr = (q * 1024 + tid) < cN;
      bool match = inr && (bits == 0 || (u >> (32 - bits)) == prefix);
      bool isz = match && (u == 0u);
      bool nz = match && (u != 0u);
      // zeros all hit bin 0 -> aggregate to one atomic per wave
      unsigned long long mz = __ballot(isz);
      if (isz && lane == (__ffsll((long long)mz) - 1))
        atomicAdd(&hist[0], (unsigned)__popcll(mz));
      if (nz) atomicAdd(&hist[(u >> shift) & ((1u << nb) - 1u)], 1u);
    }
    __syncthreads();
    // hierarchical suffix scan over 2048 bins: pair-sum -> in-wave shfl suffix
    // -> 16 wave totals -> broadcast add. 3 barriers total.
    unsigned h0 = hist[2 * tid];
    unsigned h1 = hist[2 * tid + 1];
    unsigned s2 = h0 + h1;
#pragma unroll
    for (int s = 1; s < 64; s <<= 1) {
      unsigned t = __shfl_down(s2, s);
      s2 += (lane + s < 64) ? t : 0u;
    }
    if (lane == 0) wtot[wv] = s2;             // wave total (inclusive suffix at lane 0)
    __syncthreads();
    unsigned above = 0;
    for (int w2 = wv + 1; w2 < 16; ++w2) above += wtot[w2];
    unsigned S_even = above + s2;             // suffix(bin 2*tid)
    unsigned S_odd = S_even - h0;             // suffix(bin 2*tid+1)
    unsigned S_next = S_odd - h1;             // suffix(bin 2*tid+2); 0 at tid=1023
    if (S_even >= rank && S_odd < rank) { sh_T = 2u * tid; sh_newrank = rank - S_odd; sh_E = h0; }
    if (S_odd >= rank && S_next < rank) { sh_T = 2u * tid + 1u; sh_newrank = rank - S_next; sh_E = h1; }
    __syncthreads();
    unsigned T = sh_T;
    unsigned nr = sh_newrank;
    E = sh_E;
    gtc += rank - nr;
    rank = nr;
    prefix = (prefix << nb) | T;
    bits += nb;
    __syncthreads();           // hist reused next round
    if (gtc + E <= 1024u) break;
  }

  bool tiepath = (gtc + E > 1024u);   // only possible at bits==32 (exact ties)
  unsigned pivotLo = (bits >= 32) ? prefix : (prefix << (32 - bits));
  cand[tid] = (unsigned long long)tid;   // distinct filler keys, high32 = 0
  eqbuf[tid] = 0xFFFFFFFFu;
  if (tid == 0) sh_cnt = 0u;
  __syncthreads();

  if (!tiepath) {
#pragma unroll
    for (int q = 0; q < NIT; ++q) {
      int i = q * 1024 + tid;
      unsigned u = uv[q];
      bool m = (i < cN) && (u >= pivotLo);
      unsigned long long mb = __ballot(m);
      if (m) {
        int ldr = __ffsll((long long)mb) - 1;
        unsigned base = 0;
        if (lane == ldr) base = atomicAdd(&sh_cnt, (unsigned)__popcll(mb));
        base = __shfl(base, ldr);
        unsigned pos = base + (unsigned)__popcll(mb & ((1ull << lane) - 1ull));
        if (pos < 1024u)
          cand[pos] = ((unsigned long long)u << 32) |
                      (unsigned long long)(0xFFFFFFFFu - (unsigned)i);
      }
    }
    __syncthreads();
  } else {
    // exact-tie fallback: u > P into cand, u == P smallest indices appended
    unsigned P = prefix;
#pragma unroll
    for (int q = 0; q < NIT; ++q) {
      int i = q * 1024 + tid;
      unsigned u = uv[q];
      bool gt = (i < cN) && (u > P);
      unsigned long long mb = __ballot(gt);
      if (gt) {
        int ldr = __ffsll((long long)mb) - 1;
        unsigned base = 0;
        if (lane == ldr) base = atomicAdd(&sh_cnt, (unsigned)__popcll(mb));
        base = __shfl(base, ldr);
        unsigned pos = base + (unsigned)__popcll(mb & ((1ull << lane) - 1ull));
        if (pos < 1024u)
          cand[pos] = ((unsigned long long)u << 32) |
                      (unsigned long long)(0xFFFFFFFFu - (unsigned)i);
      }
    }
    __syncthreads();
    if (tid == 0) sh_E = 0u;
    __syncthreads();
#pragma unroll
    for (int q = 0; q < NIT; ++q) {
      int i = q * 1024 + tid;
      unsigned u = uv[q];
      bool eq = (i < cN) && (u == P);
      unsigned long long mb = __ballot(eq);
      if (eq) {
        int ldr = __ffsll((long long)mb) - 1;
        unsigned base = 0;
        if (lane == ldr) base = atomicAdd(&sh_E, (unsigned)__popcll(mb));
        base = __shfl(base, ldr);
        unsigned pos = base + (unsigned)__popcll(mb & ((1ull << lane) - 1ull));
        if (pos < 1024u) eqbuf[pos] = (unsigned)i;
      }
    }
    __syncthreads();
    sort1024_u32_asc(eqbuf, tid);
    int need = (int)cK - (int)gtc;
    for (int t = tid; t < need; t += 1024) {
      unsigned idx = eqbuf[t];
      if (idx != 0xFFFFFFFFu)
        cand[gtc + (unsigned)t] = ((unsigned long long)P << 32) |
                                  (unsigned long long)(0xFFFFFFFFu - idx);
    }
    __syncthreads();
  }

  // ---- rank-by-count, 2-D split: 4 j-groups x 4 k-groups (R10) ----
  {
    int jg = wv & 3, kg = wv >> 2;
    unsigned long long myv0 = cand[jg * 256 + 0 * 64 + lane];
    unsigned long long myv1 = cand[jg * 256 + 1 * 64 + lane];
    unsigned long long myv2 = cand[jg * 256 + 2 * 64 + lane];
    unsigned long long myv3 = cand[jg * 256 + 3 * 64 + lane];
    unsigned c0 = 0, c1 = 0, c2 = 0, c3 = 0;
    int k0 = kg * 256;
#pragma unroll 4
    for (int k = 0; k < 256; ++k) {
      unsigned long long ck = cand[k0 + k];   // wave-uniform broadcast read
      c0 += (ck > myv0) ? 1u : 0u;
      c1 += (ck > myv1) ? 1u : 0u;
      c2 += (ck > myv2) ? 1u : 0u;
      c3 += (ck > myv3) ? 1u : 0u;
    }
    praw[kg][jg * 256 + 0 * 64 + lane] = c0;
    praw[kg][jg * 256 + 1 * 64 + lane] = c1;
    praw[kg][jg * 256 + 2 * 64 + lane] = c2;
    praw[kg][jg * 256 + 3 * 64 + lane] = c3;
  }
  __syncthreads();
  unsigned rk = praw[0][tid] + praw[1][tid] + praw[2][tid] + praw[3][tid];
  unsigned long long my = cand[tid];
  if (rk < (unsigned)cK) {
    unsigned uhi = (unsigned)(my >> 32);
    int idx = (int)(0xFFFFFFFFu - (unsigned)(my & 0xFFFFFFFFull));
    topidx[img * cK + (int)rk] = (uhi > 0u) ? idx : -1;
  }
}

// ---------------- kernel 3: gather (standalone, 4000 waves; no validv) -------
__global__ __launch_bounds__(256) void k_gather(const float* __restrict__ in,
                                                const int* __restrict__ topidx,
                                                float4* __restrict__ boxes,
                                                float* __restrict__ area,
                                                float* __restrict__ objv,
                                                float* __restrict__ confv,
                                                int* __restrict__ clsv) {
  int wid = (int)((blockIdx.x * 256u + threadIdx.x) >> 6);
  int lane = threadIdx.x & 63;
  if (wid >= cB * cK) return;
  int img = wid / cK;
  int idx = topidx[wid];
  if (idx < 0) {
    if (lane == 0) {
      boxes[wid] = make_float4(0.f, 0.f, 0.f, 0.f);
      area[wid] = 0.f; objv[wid] = 0.f; confv[wid] = 0.f;
      clsv[wid] = -1;
    }
    return;
  }
  const float* row = in + ((size_t)img * cN + (size_t)idx) * cROW;
  float v = row[5 + lane];
  int ci = lane;
  if (lane < 16) {
    float v2 = row[69 + lane];
    if (v2 > v) { v = v2; ci = 64 + lane; }
  }
#pragma unroll
  for (int m = 1; m < 64; m <<= 1) {
    float ov = __shfl_xor(v, m);
    int oc = __shfl_xor(ci, m);
    if (ov > v || (ov == v && oc < ci)) { v = ov; ci = oc; }
  }
  if (lane == 0) {
    float cx = row[0], cy = row[1], w = row[2], h = row[3], ob = row[4];
    float hw = w * 0.5f, hh = h * 0.5f;
    float x1 = cx - hw, y1 = cy - hh, x2 = cx + hw, y2 = cy + hh;
    boxes[wid] = make_float4(x1, y1, x2, y2);
    area[wid] = fmaxf(x2 - x1, 0.f) * fmaxf(y2 - y1, 0.f);
    objv[wid] = ob; confv[wid] = v; clsv[wid] = ci;
  }
}

// ---------------- kernel 4: suppress bitmask, TRANSPOSED output ----------------
// St[img][w][i] (i padded to 1024): word w of suppress-row i. (R3 form.)
__global__ __launch_bounds__(256) void k_suppress(const float4* __restrict__ boxes,
                                                  const float* __restrict__ area,
                                                  const int* __restrict__ clsv,
                                                  unsigned* __restrict__ St) {
  // +(i>>5) padding: inner-loop bank = (w+bit)%32 -> conflict-free
  __shared__ float sx1[1056], sy1[1056], sx2[1056], sy2[1056], sar[1056];
  __shared__ int scls[1056];
  int img = blockIdx.x >> 7;            // / 128
  int rb = (blockIdx.x & 127) * 8;      // 128 blocks x 8 rows = 1024 rows
  int tid = threadIdx.x;
  for (int i = tid; i < 1024; i += 256) {
    int p = i + (i >> 5);
    if (i < cK) {
      float4 b = boxes[img * cK + i];
      sx1[p] = b.x; sy1[p] = b.y; sx2[p] = b.z; sy2[p] = b.w;
      sar[p] = area[img * cK + i];
      scls[p] = clsv[img * cK + i];
    } else {
      sx1[p] = 0.f; sy1[p] = 0.f; sx2[p] = 0.f; sy2[p] = 0.f; sar[p] = 0.f;
      scls[p] = -2;
    }
  }
  __syncthreads();
  int i = rb + (tid >> 5);
  int w = tid & 31;
  int pi = i + (i >> 5);
  float bx1 = sx1[pi], by1 = sy1[pi], bx2 = sx2[pi], by2 = sy2[pi], ba = sar[pi];
  int bc = scls[pi];
  unsigned word = 0u;
#pragma unroll 4
  for (int bit = 0; bit < 32; ++bit) {
    int pj = 33 * w + bit;
    float xx1 = fmaxf(bx1, sx1[pj]);
    float yy1 = fmaxf(by1, sy1[pj]);
    float xx2 = fminf(bx2, sx2[pj]);
    float yy2 = fminf(by2, sy2[pj]);
    float inter = fmaxf(xx2 - xx1, 0.f) * fmaxf(yy2 - yy1, 0.f);
    float uni = ba + sar[pj] - inter;
    float iou = inter / (uni + 1e-16f);
    if (iou > NMS_T && bc == scls[pj]) word |= (1u << bit);
  }
  St[((size_t)(img * 32 + w)) * 1024 + (size_t)i] = word;
}

// ---------------- kernel 5: word-batched greedy NMS + masked write ----------------
// Greedy on wave 0 (compile-time-indexed bufA/bufB stay in VGPRs); R14: output
// write phase uses all 256 threads (was 64) to cut the scattered-store tail 4x.
__device__ __forceinline__ unsigned u4c(const uint4& v, int c) {
  return c == 0 ? v.x : c == 1 ? v.y : c == 2 ? v.z : v.w;
}

__device__ __forceinline__ void nms_load(const uint4* __restrict__ colv, int b,
                                         uint4 (&buf)[8]) {
#pragma unroll
  for (int q = 0; q < 8; ++q) buf[q] = colv[8 * b + q];
}

__device__ __forceinline__ void nms_proc(int b, int lane, unsigned& kw,
                                         const uint4 (&W)[8]) {
  unsigned dec = 0u;
  if (lane == b) {
    unsigned kwb = kw;
#pragma unroll
    for (int t = 0; t < 32; ++t) {
      if ((kwb >> t) & 1u) {
        dec |= (1u << t);
        unsigned rw = u4c(W[t >> 2], t & 3);
        unsigned mgt = (t == 31) ? 0u : (0xFFFFFFFFu << (t + 1));
        kwb &= ~(rw & mgt);   // kill only later rows within this word
      }
    }
    kw = kwb;
  }
  dec = __shfl(dec, b);       // broadcast the 32 decisions
  if (dec != 0u && lane > b) {   // skip apply when no kept rows in word b
#pragma unroll
    for (int t = 0; t < 32; ++t) {
      unsigned sel = 0u - ((dec >> t) & 1u);
      kw &= ~(u4c(W[t >> 2], t & 3) & sel);
    }
  }
}

__global__ __launch_bounds__(256) void k_nms(const unsigned* __restrict__ St,
                                             const int* __restrict__ topidx,
                                             const float4* __restrict__ boxes,
                                             const float* __restrict__ objv,
                                             const float* __restrict__ confv,
                                             const int* __restrict__ clsv,
                                             float* __restrict__ out) {
  __shared__ unsigned keep_sh[32];
  int img = blockIdx.x;
  int tid = threadIdx.x;
  int lane = tid & 63;
  if (tid < 32) {
    const uint4* colv = (const uint4*)(St + ((size_t)(img * 32 + tid)) * 1024);
    // valid mask from 8 coalesced int4 loads of topidx (>=0 means valid)
    unsigned kw = 0u;
    const int4* v4 = (const int4*)(topidx + img * cK);
#pragma unroll
    for (int q = 0; q < 8; ++q) {
      int k0 = (tid << 5) + 4 * q;
      if (k0 < cK) {
        int4 t = v4[tid * 8 + q];
        kw |= (unsigned)(t.x >= 0) << (4 * q + 0);
        kw |= (unsigned)(t.y >= 0) << (4 * q + 1);
        kw |= (unsigned)(t.z >= 0) << (4 * q + 2);
        kw |= (unsigned)(t.w >= 0) << (4 * q + 3);
      }
    }
    uint4 bufA[8], bufB[8];
    nms_load(colv, 0, bufA);
    for (int b = 0; b < 32; b += 2) {
      if (b + 1 < 32) nms_load(colv, b + 1, bufB);
      nms_proc(b, lane, kw, bufA);
      if (b + 2 < 32) nms_load(colv, b + 2, bufA);
      nms_proc(b + 1, lane, kw, bufB);
    }
    keep_sh[tid] = kw;
  }
  __syncthreads();
  for (int k = tid; k < cK; k += 256) {
    bool kp = ((keep_sh[k >> 5] >> (k & 31)) & 1u) != 0u;
    size_t o = ((size_t)img * cK + (size_t)k) * 7;
    if (kp) {
      float4 b = boxes[img * cK + k];
      out[o + 0] = b.x; out[o + 1] = b.y; out[o + 2] = b.z; out[o + 3] = b.w;
      out[o + 4] = objv[img * cK + k];
      out[o + 5] = confv[img * cK + k];
      out[o + 6] = (float)clsv[img * cK + k];
    } else {
      out[o + 0] = 0.f; out[o + 1] = 0.f; out[o + 2] = 0.f; out[o + 3] = 0.f;
      out[o + 4] = 0.f; out[o + 5] = 0.f; out[o + 6] = 0.f;
    }
  }
}

extern "C" void kernel_launch(void* const* d_in, const int* in_sizes, int n_in,
                              void* d_out, int out_size, void* d_ws, size_t ws_size,
                              hipStream_t stream) {
  const float* in = (const float*)d_in[0];
  float* out = (float*)d_out;
  char* ws = (char*)d_ws;
  size_t off = 0;
  auto take = [&](size_t bytes) {
    size_t r = off;
    off += (bytes + 255) & ~(size_t)255;
    return r;
  };
  unsigned* ukey = (unsigned*)(ws + take((size_t)cB * cN * 4));
  int* topidx = (int*)(ws + take((size_t)cB * cK * 4));
  float4* boxes = (float4*)(ws + take((size_t)cB * cK * 16));
  float* area = (float*)(ws + take((size_t)cB * cK * 4));
  float* objv = (float*)(ws + take((size_t)cB * cK * 4));
  float* confv = (float*)(ws + take((size_t)cB * cK * 4));
  int* clsv = (int*)(ws + take((size_t)cB * cK * 4));
  unsigned* St = (unsigned*)(ws + take((size_t)cB * 32 * 1024 * 4));

  int nrows = cB * cN;
  int blocks1 = (nrows + 127) / 128;          // 128 rows per block
  k_score<<<blocks1, 256, 0, stream>>>(in, ukey);
  k_topk<<<cB, 1024, 0, stream>>>(ukey, topidx);
  int waves3 = cB * cK;
  k_gather<<<(waves3 * 64 + 255) / 256, 256, 0, stream>>>(in, topidx, boxes, area,
                                                          objv, confv, clsv);
  k_suppress<<<cB * 128, 256, 0, stream>>>(boxes, area, clsv, St);
  k_nms<<<cB, 256, 0, stream>>>(St, topidx, boxes, objv, confv, clsv, out);
}